// Round 6
// baseline (515.849 us; speedup 1.0000x reference)
//
#include <hip/hip_runtime.h>
#include <stdint.h>

typedef unsigned int  uint32;
typedef unsigned short u16;

typedef short bfx8 __attribute__((ext_vector_type(8)));
typedef float f32x4 __attribute__((ext_vector_type(4)));
typedef float f32x2 __attribute__((ext_vector_type(2)));

#define NBP 256          // padded bucket count (N <= 65536)
#define CH  2048         // edges per partition chunk

// ---------- bf16 helpers ----------
__device__ __forceinline__ float b2f(u16 u) {
    union { uint32 i; float f; } v; v.i = ((uint32)u) << 16; return v.f;
}
__device__ __forceinline__ u16 f2b(float f) {
    union { float f; uint32 i; } v; v.f = f;
    uint32 u = v.i;
    return (u16)((u + 0x7fffu + ((u >> 16) & 1u)) >> 16);   // RNE
}
__device__ __forceinline__ float blo(uint32 u) {
    union { uint32 i; float f; } v; v.i = u << 16; return v.f;
}
__device__ __forceinline__ float bhi(uint32 u) {
    union { uint32 i; float f; } v; v.i = u & 0xffff0000u; return v.f;
}
__device__ __forceinline__ uint32 packbf(float a, float b) {
    return (uint32)f2b(a) | ((uint32)f2b(b) << 16);
}
__device__ __forceinline__ void splitf(float x, u16& h, u16& l) {
    h = f2b(x);
    l = f2b(x - b2f(h));
}
__device__ __forceinline__ void split8(const float* __restrict__ p, bfx8& hi, bfx8& lo) {
    f32x4 a = *(const f32x4*)p;
    f32x4 b = *(const f32x4*)(p + 4);
    float x[8] = {a[0], a[1], a[2], a[3], b[0], b[1], b[2], b[3]};
#pragma unroll
    for (int j = 0; j < 8; ++j) {
        u16 h, l; splitf(x[j], h, l);
        hi[j] = (short)h; lo[j] = (short)l;
    }
}

// ---------- pass A: packed bucket histograms || weight split ----------
__global__ __launch_bounds__(256) void k_preA(
    const int* __restrict__ row, const int* __restrict__ col, int E, int Gh,
    int* __restrict__ cntC, int* __restrict__ cntR,
    const float* __restrict__ W1, const float* __restrict__ W2,
    const float* __restrict__ W3, const float* __restrict__ fcW,
    u16* __restrict__ WTh, u16* __restrict__ WTl, int WTN) {
    if ((int)blockIdx.x < Gh) {
        __shared__ int hp[NBP];        // packed: col-count low16, row-count high16
        int t = threadIdx.x;
        hp[t] = 0;
        __syncthreads();
        int base = blockIdx.x * CH;
        int n = E - base; if (n > CH) n = CH;
        for (int i = t; i < n; i += 256) {
            int r = row[base + i], c = col[base + i];
            atomicAdd(&hp[c >> 8], 1);
            atomicAdd(&hp[r >> 8], 0x10000);
        }
        __syncthreads();
        int v = hp[t];
        if (v & 0xffff) atomicAdd(&cntC[t], v & 0xffff);
        if (v >> 16)    atomicAdd(&cntR[t], v >> 16);
        return;
    }
    int i = ((int)blockIdx.x - Gh) * 256 + threadIdx.x;
    if (i >= WTN) return;
    float w;
    if (i < 3 * 16384) {
        int m = i >> 14, j = i & 16383;     // j = fo*128 + fi
        int fo = j >> 7, fi = j & 127;
        const float* W = (m == 0) ? W1 : (m == 1) ? W2 : W3;
        w = W[fi * 128 + fo];
    } else {
        int j = i - 3 * 16384;
        int fo = j >> 7, fi = j & 127;
        w = fcW[fi * 64 + fo];
    }
    u16 h, l; splitf(w, h, l);
    WTh[i] = h; WTl[i] = l;
}

// ---------- pass B: 1 block, scans bucket counts -> offsets + cursors ----------
__global__ __launch_bounds__(256) void k_scanB(
    const int* __restrict__ cntC, const int* __restrict__ cntR,
    int* __restrict__ bOffC, int* __restrict__ bOffR,
    int* __restrict__ curC, int* __restrict__ curR, int NB) {
    int t = threadIdx.x;
    int lane = t & 63, wid = t >> 6;
    __shared__ int wsum[4];
    for (int m = 0; m < 2; ++m) {
        const int* cnt = m ? cntR : cntC;
        int* bOff = m ? bOffR : bOffC;
        int* cur  = m ? curR  : curC;
        int v = (t < NB) ? cnt[t] : 0;
        int x = v;
#pragma unroll
        for (int d = 1; d < 64; d <<= 1) {
            int u = __shfl_up(x, d);
            if (lane >= d) x += u;
        }
        if (lane == 63) wsum[wid] = x;
        __syncthreads();
        int add = 0;
        for (int i = 0; i < wid; ++i) add += wsum[i];
        int ex = x + add - v;
        if (t <= NB) bOff[t] = ex;
        cur[t] = ex;
        __syncthreads();
    }
}

// ---------- gemm body (fp32 A, split in-kernel): G = (A @ W) [* dinv], bf16 out --------
__device__ __forceinline__ void gemm128_f32_body(
    const float* __restrict__ A, const u16* __restrict__ WTh, const u16* __restrict__ WTl,
    const float* __restrict__ dinv, u16* __restrict__ G, int M, int blk) {
    const int lane = threadIdx.x & 63;
    const int q = lane >> 4, l = lane & 15;
    int rbase = blk * 128 + (threadIdx.x >> 6) * 32;
    if (rbase >= M) return;
    int r0 = rbase + l;      if (r0 >= M) r0 = M - 1;
    int r1 = rbase + 16 + l; if (r1 >= M) r1 = M - 1;

    f32x4 acc[2][8];
#pragma unroll
    for (int i = 0; i < 2; ++i)
#pragma unroll
        for (int j = 0; j < 8; ++j) acc[i][j] = (f32x4){0.f, 0.f, 0.f, 0.f};

#pragma unroll
    for (int kc = 0; kc < 4; ++kc) {
        int k0 = kc * 32 + q * 8;
        bfx8 ah0, al0, ah1, al1;
        split8(A + (size_t)r0 * 128 + k0, ah0, al0);
        split8(A + (size_t)r1 * 128 + k0, ah1, al1);
#pragma unroll
        for (int ct = 0; ct < 8; ++ct) {
            bfx8 bh = *(const bfx8*)(WTh + (ct * 16 + l) * 128 + k0);
            bfx8 bl = *(const bfx8*)(WTl + (ct * 16 + l) * 128 + k0);
            acc[0][ct] = __builtin_amdgcn_mfma_f32_16x16x32_bf16(ah0, bh, acc[0][ct], 0, 0, 0);
            acc[0][ct] = __builtin_amdgcn_mfma_f32_16x16x32_bf16(ah0, bl, acc[0][ct], 0, 0, 0);
            acc[0][ct] = __builtin_amdgcn_mfma_f32_16x16x32_bf16(al0, bh, acc[0][ct], 0, 0, 0);
            acc[1][ct] = __builtin_amdgcn_mfma_f32_16x16x32_bf16(ah1, bh, acc[1][ct], 0, 0, 0);
            acc[1][ct] = __builtin_amdgcn_mfma_f32_16x16x32_bf16(ah1, bl, acc[1][ct], 0, 0, 0);
            acc[1][ct] = __builtin_amdgcn_mfma_f32_16x16x32_bf16(al1, bh, acc[1][ct], 0, 0, 0);
        }
    }
#pragma unroll
    for (int rs = 0; rs < 2; ++rs) {
#pragma unroll
        for (int rr = 0; rr < 4; ++rr) {
            int rw = rbase + rs * 16 + q * 4 + rr;
            if (rw < M) {
                float dv = dinv ? dinv[rw] : 1.0f;
#pragma unroll
                for (int ct = 0; ct < 8; ++ct)
                    G[(size_t)rw * 128 + ct * 16 + l] = f2b(acc[rs][ct][rr] * dv);
            }
        }
    }
}

// ---------- gemm from hi/lo bf16 planes: G = (A @ W) * dinv ----------
__global__ __launch_bounds__(256) void k_gemm128_pl(
    const u16* __restrict__ Ah, const u16* __restrict__ Al,
    const u16* __restrict__ WTh, const u16* __restrict__ WTl,
    const float* __restrict__ dinv, u16* __restrict__ G, int M) {
    const int lane = threadIdx.x & 63;
    const int q = lane >> 4, l = lane & 15;
    int rbase = blockIdx.x * 128 + (threadIdx.x >> 6) * 32;
    if (rbase >= M) return;
    int r0 = rbase + l;      if (r0 >= M) r0 = M - 1;
    int r1 = rbase + 16 + l; if (r1 >= M) r1 = M - 1;

    f32x4 acc[2][8];
#pragma unroll
    for (int i = 0; i < 2; ++i)
#pragma unroll
        for (int j = 0; j < 8; ++j) acc[i][j] = (f32x4){0.f, 0.f, 0.f, 0.f};

#pragma unroll
    for (int kc = 0; kc < 4; ++kc) {
        int k0 = kc * 32 + q * 8;
        bfx8 ah0 = *(const bfx8*)(Ah + (size_t)r0 * 128 + k0);
        bfx8 al0 = *(const bfx8*)(Al + (size_t)r0 * 128 + k0);
        bfx8 ah1 = *(const bfx8*)(Ah + (size_t)r1 * 128 + k0);
        bfx8 al1 = *(const bfx8*)(Al + (size_t)r1 * 128 + k0);
#pragma unroll
        for (int ct = 0; ct < 8; ++ct) {
            bfx8 bh = *(const bfx8*)(WTh + (ct * 16 + l) * 128 + k0);
            bfx8 bl = *(const bfx8*)(WTl + (ct * 16 + l) * 128 + k0);
            acc[0][ct] = __builtin_amdgcn_mfma_f32_16x16x32_bf16(ah0, bh, acc[0][ct], 0, 0, 0);
            acc[0][ct] = __builtin_amdgcn_mfma_f32_16x16x32_bf16(ah0, bl, acc[0][ct], 0, 0, 0);
            acc[0][ct] = __builtin_amdgcn_mfma_f32_16x16x32_bf16(al0, bh, acc[0][ct], 0, 0, 0);
            acc[1][ct] = __builtin_amdgcn_mfma_f32_16x16x32_bf16(ah1, bh, acc[1][ct], 0, 0, 0);
            acc[1][ct] = __builtin_amdgcn_mfma_f32_16x16x32_bf16(ah1, bl, acc[1][ct], 0, 0, 0);
            acc[1][ct] = __builtin_amdgcn_mfma_f32_16x16x32_bf16(al1, bh, acc[1][ct], 0, 0, 0);
        }
    }
#pragma unroll
    for (int rs = 0; rs < 2; ++rs) {
#pragma unroll
        for (int rr = 0; rr < 4; ++rr) {
            int rw = rbase + rs * 16 + q * 4 + rr;
            if (rw < M) {
                float dv = dinv[rw];
#pragma unroll
                for (int ct = 0; ct < 8; ++ct)
                    G[(size_t)rw * 128 + ct * 16 + l] = f2b(acc[rs][ct][rr] * dv);
            }
        }
    }
}

// ---------- pass C: dual-direction bucket partition (blocks < Gc) || gemm0 ----------
__global__ __launch_bounds__(256) void k_partC_gemm0(
    const int* __restrict__ row, const int* __restrict__ col, int E, int Gc,
    int* __restrict__ curC, int* __restrict__ curR,
    uint32* __restrict__ partC, uint32* __restrict__ partR,
    const float* __restrict__ A, const u16* __restrict__ WTh, const u16* __restrict__ WTl,
    u16* __restrict__ G, int M) {
    if ((int)blockIdx.x >= Gc) {
        gemm128_f32_body(A, WTh, WTl, nullptr, G, M, (int)blockIdx.x - Gc);
        return;
    }
    __shared__ uint32 stagedC[CH], stagedR[CH];
    __shared__ int hp[NBP], expk[NBP], curp[NBP], runC[NBP], runR[NBP];
    __shared__ int wsum[4];
    int t = threadIdx.x;
    int lane = t & 63, wid = t >> 6;
    int base = blockIdx.x * CH;
    int n = E - base; if (n > CH) n = CH;

    int er[8], ec[8];
#pragma unroll
    for (int j = 0; j < 8; ++j) {
        int i = t + j * 256;
        if (i < n) { er[j] = row[base + i]; ec[j] = col[base + i]; }
        else er[j] = -1;
    }
    hp[t] = 0;
    __syncthreads();
#pragma unroll
    for (int j = 0; j < 8; ++j) {
        if (er[j] >= 0) {
            atomicAdd(&hp[ec[j] >> 8], 1);
            atomicAdd(&hp[er[j] >> 8], 0x10000);
        }
    }
    __syncthreads();
    int v = hp[t];
    int x = v;
#pragma unroll
    for (int d = 1; d < 64; d <<= 1) {
        int u = __shfl_up(x, d);
        if (lane >= d) x += u;
    }
    if (lane == 63) wsum[wid] = x;
    __syncthreads();
    int add = 0;
    for (int i = 0; i < wid; ++i) add += wsum[i];
    int ex = x + add - v;
    expk[t] = ex;
    curp[t] = ex;
    int vC = v & 0xffff, vR = v >> 16;
    runC[t] = vC ? atomicAdd(&curC[t], vC) : 0;
    runR[t] = vR ? atomicAdd(&curR[t], vR) : 0;
    __syncthreads();
#pragma unroll
    for (int j = 0; j < 8; ++j) {
        if (er[j] >= 0) {
            int cb = ec[j] >> 8, rb = er[j] >> 8;
            int pC = atomicAdd(&curp[cb], 1) & 0xffff;
            stagedC[pC] = ((uint32)ec[j] << 16) | (uint32)er[j];
            int pR = atomicAdd(&curp[rb], 0x10000) >> 16;
            stagedR[pR] = ((uint32)er[j] << 16) | (uint32)ec[j];
        }
    }
    __syncthreads();
    for (int i = t; i < n; i += 256) {
        uint32 pv = stagedC[i];
        int b = pv >> 24;
        partC[runC[b] + (i - (expk[b] & 0xffff))] = pv;
    }
    for (int i = t; i < n; i += 256) {
        uint32 pv = stagedR[i];
        int b = pv >> 24;
        partR[runR[b] + (i - (expk[b] >> 16))] = pv;
    }
}

// ---------- pass D: per-bucket CSR fill + dinv (from in-degree histogram) ----------
__global__ __launch_bounds__(256) void k_fillD(
    const uint32* __restrict__ partC, const uint32* __restrict__ partR,
    const int* __restrict__ bOffC, const int* __restrict__ bOffR,
    int* __restrict__ off_in, int* __restrict__ off_out,
    u16* __restrict__ csr_src, u16* __restrict__ csr_dst,
    float* __restrict__ dinv, int NB, int N, int E) {
    int part = ((int)blockIdx.x >= NB) ? 1 : 0;
    int b = (int)blockIdx.x - part * NB;
    const uint32* arr = part ? partR : partC;
    const int* bOff   = part ? bOffR : bOffC;
    int* offA         = part ? off_out : off_in;
    u16* csr          = part ? csr_dst : csr_src;
    int t = threadIdx.x;
    int lane = t & 63, wid = t >> 6;
    int base = bOff[b], end = bOff[b + 1];
    __shared__ int cnt[NBP], cur[NBP];
    __shared__ int wsum[4];
    cnt[t] = 0;
    __syncthreads();
    for (int i = base + t; i < end; i += 256)
        atomicAdd(&cnt[(arr[i] >> 16) & 255], 1);
    __syncthreads();
    int v = cnt[t];
    int x = v;
#pragma unroll
    for (int d = 1; d < 64; d <<= 1) {
        int u = __shfl_up(x, d);
        if (lane >= d) x += u;
    }
    if (lane == 63) wsum[wid] = x;
    __syncthreads();
    int add = 0;
    for (int i = 0; i < wid; ++i) add += wsum[i];
    int ex = x + add - v;
    cur[t] = ex;
    int node = (b << 8) + t;
    if (node < N) {
        offA[node] = base + ex;
        if (part == 0) dinv[node] = rsqrtf((float)(v + 1));   // in-degree + self loop
    }
    if (b == 0 && t == 0) offA[N] = E;
    __syncthreads();
    for (int i = base + t; i < end; i += 256) {
        uint32 pv = arr[i];
        int local = (pv >> 16) & 255;
        int pos = atomicAdd(&cur[local], 1);
        csr[base + pos] = (u16)(pv & 0xffffu);
    }
}

// ---------- feature-split GCN aggregate (4 passes, per-pass 64B line / row) ----------
// wave = 4 nodes x 16 lanes; pass p touches word range [p*16, p*16+16) of each row.
// MODE 0: g unscaled -> apply dinv[src] per neighbor; bf16-packed out (t0)
// MODE 1: g pre-scaled; hi/lo plane out
template <int MODE>
__global__ __launch_bounds__(256) void k_agg4(
    const uint32* __restrict__ g, const u16* __restrict__ csr,
    const int* __restrict__ off, const float* __restrict__ dinv,
    const f32x2* __restrict__ bias, uint32* __restrict__ outH,
    uint32* __restrict__ outL, int n, int nb) {
    int pass = blockIdx.x / nb;
    int blk  = blockIdx.x - pass * nb;
    int gi = (threadIdx.x & 63) >> 4;
    int fl = threadIdx.x & 15;
    int w = blk * 16 + (threadIdx.x >> 6) * 4 + gi;
    bool valid = (w < n);
    if (!valid) w = n - 1;
    int wi = pass * 16 + fl;
    int e0 = off[w], e1 = off[w + 1];
    int deg = e1 - e0;
    uint32 sv = g[(size_t)w * 64 + wi];
    float dc = dinv[w];
    float s0, s1;
    if (MODE == 0) { s0 = blo(sv) * dc; s1 = bhi(sv) * dc; }
    else           { s0 = blo(sv);      s1 = bhi(sv); }
    int m = max(deg, __shfl_xor(deg, 16));
    m = max(m, __shfl_xor(m, 32));
    for (int it = 0; it < m; it += 4) {
#pragma unroll
        for (int k = 0; k < 4; ++k) {
            int tt = it + k;
            bool a = tt < deg;
            int idx = a ? (int)csr[e0 + tt] : w;
            uint32 vv = g[(size_t)idx * 64 + wi];
            if (MODE == 0) {
                float dm = a ? dinv[idx] : 0.f;
                s0 = fmaf(blo(vv), dm, s0);
                s1 = fmaf(bhi(vv), dm, s1);
            } else {
                vv = a ? vv : 0u;
                s0 += blo(vv); s1 += bhi(vv);
            }
        }
    }
    f32x2 bb = bias[wi];
    float o0 = fmaxf(fmaf(s0, dc, bb[0]), 0.f);
    float o1 = fmaxf(fmaf(s1, dc, bb[1]), 0.f);
    if (!valid) return;
    if (MODE == 0) {
        outH[(size_t)w * 64 + wi] = packbf(o0, o1);
    } else {
        u16 h0, l0, h1, l1;
        splitf(o0, h0, l0);
        splitf(o1, h1, l1);
        outH[(size_t)w * 64 + wi] = (uint32)h0 | ((uint32)h1 << 16);
        outL[(size_t)w * 64 + wi] = (uint32)l0 | ((uint32)l1 << 16);
    }
}

// ---------- feature-split neighbor mean (4 passes) -> hi/lo planes ----------
__global__ __launch_bounds__(256) void k_mean4(
    const uint32* __restrict__ h, const u16* __restrict__ csr,
    const int* __restrict__ off, uint32* __restrict__ outH,
    uint32* __restrict__ outL, int n, int nb) {
    int pass = blockIdx.x / nb;
    int blk  = blockIdx.x - pass * nb;
    int gi = (threadIdx.x & 63) >> 4;
    int fl = threadIdx.x & 15;
    int w = blk * 16 + (threadIdx.x >> 6) * 4 + gi;
    bool valid = (w < n);
    if (!valid) w = n - 1;
    int wi = pass * 16 + fl;
    int e0 = off[w], e1 = off[w + 1];
    int deg = e1 - e0;
    uint32 sv = h[(size_t)w * 64 + wi];
    float s0 = 0.f, s1 = 0.f;
    int m = max(deg, __shfl_xor(deg, 16));
    m = max(m, __shfl_xor(m, 32));
    for (int it = 0; it < m; it += 4) {
#pragma unroll
        for (int k = 0; k < 4; ++k) {
            int tt = it + k;
            bool a = tt < deg;
            int idx = a ? (int)csr[e0 + tt] : w;
            uint32 vv = h[(size_t)idx * 64 + wi];
            vv = a ? vv : 0u;
            s0 += blo(vv); s1 += bhi(vv);
        }
    }
    float o0, o1;
    if (deg > 0) {
        float inv = 1.f / (float)deg;
        o0 = s0 * inv; o1 = s1 * inv;
    } else {
        o0 = blo(sv); o1 = bhi(sv);
    }
    if (!valid) return;
    u16 ha, la, hb, lb;
    splitf(o0, ha, la);
    splitf(o1, hb, lb);
    outH[(size_t)w * 64 + wi] = (uint32)ha | ((uint32)hb << 16);
    outL[(size_t)w * 64 + wi] = (uint32)la | ((uint32)lb << 16);
}

// ---------- final: out = (w0*h0 + w1*h1 + w2*h2) @ fcW + fc_b ----------
__global__ __launch_bounds__(256) void k_final(
    const u16* __restrict__ h0h, const u16* __restrict__ h0l,
    const u16* __restrict__ h1h, const u16* __restrict__ h1l,
    const u16* __restrict__ h2h, const u16* __restrict__ h2l,
    const float* __restrict__ jkw,
    const u16* __restrict__ fcWTh, const u16* __restrict__ fcWTl,
    const float* __restrict__ fcb, float* __restrict__ out, int M) {
    float a0 = jkw[0], a1 = jkw[1], a2 = jkw[2];
    float mx = fmaxf(a0, fmaxf(a1, a2));
    float e0 = expf(a0 - mx), e1 = expf(a1 - mx), e2 = expf(a2 - mx);
    float inv = 1.f / (e0 + e1 + e2);
    float w0 = e0 * inv, w1 = e1 * inv, w2 = e2 * inv;

    const int lane = threadIdx.x & 63;
    const int q = lane >> 4, l = lane & 15;
    int rbase = blockIdx.x * 128 + (threadIdx.x >> 6) * 32;
    if (rbase >= M) return;
    int r0 = rbase + l;      if (r0 >= M) r0 = M - 1;
    int r1 = rbase + 16 + l; if (r1 >= M) r1 = M - 1;

    f32x4 acc[2][4];
#pragma unroll
    for (int i = 0; i < 2; ++i)
#pragma unroll
        for (int j = 0; j < 4; ++j) acc[i][j] = (f32x4){0.f, 0.f, 0.f, 0.f};

    union U8 { bfx8 v; u16 u[8]; };

#pragma unroll
    for (int kc = 0; kc < 4; ++kc) {
        int k0 = kc * 32 + q * 8;
        bfx8 ah[2], al[2];
        const int rr2[2] = {r0, r1};
#pragma unroll
        for (int half = 0; half < 2; ++half) {
            size_t o = (size_t)rr2[half] * 128 + k0;
            U8 x0h, x0l, x1h, x1l, x2h, x2l, rh, rl;
            x0h.v = *(const bfx8*)(h0h + o); x0l.v = *(const bfx8*)(h0l + o);
            x1h.v = *(const bfx8*)(h1h + o); x1l.v = *(const bfx8*)(h1l + o);
            x2h.v = *(const bfx8*)(h2h + o); x2l.v = *(const bfx8*)(h2l + o);
#pragma unroll
            for (int j = 0; j < 8; ++j) {
                float v0 = b2f(x0h.u[j]) + b2f(x0l.u[j]);
                float v1 = b2f(x1h.u[j]) + b2f(x1l.u[j]);
                float v2 = b2f(x2h.u[j]) + b2f(x2l.u[j]);
                float c = w0 * v0 + w1 * v1 + w2 * v2;
                u16 ch, cl; splitf(c, ch, cl);
                rh.u[j] = ch; rl.u[j] = cl;
            }
            ah[half] = rh.v; al[half] = rl.v;
        }
#pragma unroll
        for (int ct = 0; ct < 4; ++ct) {
            bfx8 bh = *(const bfx8*)(fcWTh + (ct * 16 + l) * 128 + k0);
            bfx8 bl = *(const bfx8*)(fcWTl + (ct * 16 + l) * 128 + k0);
#pragma unroll
            for (int half = 0; half < 2; ++half) {
                acc[half][ct] = __builtin_amdgcn_mfma_f32_16x16x32_bf16(ah[half], bh, acc[half][ct], 0, 0, 0);
                acc[half][ct] = __builtin_amdgcn_mfma_f32_16x16x32_bf16(ah[half], bl, acc[half][ct], 0, 0, 0);
                acc[half][ct] = __builtin_amdgcn_mfma_f32_16x16x32_bf16(al[half], bh, acc[half][ct], 0, 0, 0);
            }
        }
    }
#pragma unroll
    for (int rs = 0; rs < 2; ++rs) {
#pragma unroll
        for (int rr = 0; rr < 4; ++rr) {
            int rw = rbase + rs * 16 + q * 4 + rr;
            if (rw < M) {
#pragma unroll
                for (int ct = 0; ct < 4; ++ct) {
                    int cc = ct * 16 + l;
                    out[(size_t)rw * 64 + cc] = acc[rs][ct][rr] + fcb[cc];
                }
            }
        }
    }
}

extern "C" void kernel_launch(void* const* d_in, const int* in_sizes, int n_in,
                              void* d_out, int out_size, void* d_ws, size_t ws_size,
                              hipStream_t stream) {
    const int N = in_sizes[0] / 128;   // 50000
    const int E = in_sizes[1] / 2;     // 800000
    const int NB = (N + 255) >> 8;     // 196 buckets

    const float* x    = (const float*)d_in[0];
    const int* row    = (const int*)d_in[1];
    const int* col    = row + E;
    const float* W1   = (const float*)d_in[2];
    const float* b1   = (const float*)d_in[3];
    const float* W2   = (const float*)d_in[4];
    const float* b2   = (const float*)d_in[5];
    const float* W3   = (const float*)d_in[6];
    const float* b3   = (const float*)d_in[7];
    const float* jkw  = (const float*)d_in[8];
    const float* fcW  = (const float*)d_in[9];
    const float* fcb  = (const float*)d_in[10];
    float* outp       = (float*)d_out;

    char* ws = (char*)d_ws;
    size_t off = 0;
    auto alloc = [&](size_t bytes) -> char* {
        char* p = ws + off;
        off += (bytes + 255) & ~(size_t)255;
        return p;
    };
    int* cntC   = (int*)alloc((size_t)2 * NBP * sizeof(int));  // zero-init
    int* cntR   = cntC + NBP;
    int* bOffC  = (int*)alloc((size_t)(NBP + 1) * sizeof(int));
    int* bOffR  = (int*)alloc((size_t)(NBP + 1) * sizeof(int));
    int* curC   = (int*)alloc((size_t)NBP * sizeof(int));
    int* curR   = (int*)alloc((size_t)NBP * sizeof(int));
    int* off_in  = (int*)alloc((size_t)(N + 1) * sizeof(int));
    int* off_out = (int*)alloc((size_t)(N + 1) * sizeof(int));
    uint32* partC = (uint32*)alloc((size_t)E * sizeof(uint32));
    uint32* partR = (uint32*)alloc((size_t)E * sizeof(uint32));
    u16* csr_src = (u16*)alloc((size_t)E * sizeof(u16));
    u16* csr_dst = (u16*)alloc((size_t)E * sizeof(u16));
    float* dinv  = (float*)alloc((size_t)N * sizeof(float));
    const int WTN = 3 * 16384 + 8192;
    u16* WTh = (u16*)alloc((size_t)WTN * sizeof(u16));
    u16* WTl = (u16*)alloc((size_t)WTN * sizeof(u16));
    size_t FB = (size_t)N * 128 * sizeof(u16);
    u16* gbuf = (u16*)alloc(FB);
    u16* t0   = (u16*)alloc(FB);
    u16* h0h = (u16*)alloc(FB); u16* h0l = (u16*)alloc(FB);
    u16* h1h = (u16*)alloc(FB); u16* h1l = (u16*)alloc(FB);
    u16* h2h = (u16*)alloc(FB); u16* h2l = (u16*)alloc(FB);

    hipMemsetAsync(cntC, 0, (size_t)2 * NBP * sizeof(int), stream);

    const int B = 256;
    int Gh = (E + CH - 1) / CH;
    int Gwt = (WTN + B - 1) / B;
    k_preA<<<Gh + Gwt, B, 0, stream>>>(row, col, E, Gh, cntC, cntR,
                                       W1, W2, W3, fcW, WTh, WTl, WTN);
    k_scanB<<<1, B, 0, stream>>>(cntC, cntR, bOffC, bOffR, curC, curR, NB);

    int Gc = (E + CH - 1) / CH;
    int Gg = (N + 127) / 128;
    k_partC_gemm0<<<Gc + Gg, B, 0, stream>>>(row, col, E, Gc, curC, curR, partC, partR,
                                             x, WTh, WTl, gbuf, N);
    k_fillD<<<2 * NB, B, 0, stream>>>(partC, partR, bOffC, bOffR,
                                      off_in, off_out, csr_src, csr_dst, dinv, NB, N, E);

    int nb = (N + 15) / 16;            // node-blocks per feature pass
    int aggG = 4 * nb;                 // 4 feature passes, pass-major

    // layer 0
    k_agg4<0><<<aggG, B, 0, stream>>>((const uint32*)gbuf, csr_src, off_in, dinv,
                                      (const f32x2*)b1, (uint32*)t0, nullptr, N, nb);
    k_mean4<<<aggG, B, 0, stream>>>((const uint32*)t0, csr_dst, off_out,
                                    (uint32*)h0h, (uint32*)h0l, N, nb);
    // layer 1
    k_gemm128_pl<<<Gg, B, 0, stream>>>(h0h, h0l, WTh + 16384, WTl + 16384, dinv, gbuf, N);
    k_agg4<1><<<aggG, B, 0, stream>>>((const uint32*)gbuf, csr_src, off_in, dinv,
                                      (const f32x2*)b2, (uint32*)h1h, (uint32*)h1l, N, nb);
    // layer 2
    k_gemm128_pl<<<Gg, B, 0, stream>>>(h1h, h1l, WTh + 2 * 16384, WTl + 2 * 16384, dinv, gbuf, N);
    k_agg4<1><<<aggG, B, 0, stream>>>((const uint32*)gbuf, csr_src, off_in, dinv,
                                      (const f32x2*)b3, (uint32*)h2h, (uint32*)h2l, N, nb);
    // JK combine + final linear
    k_final<<<Gg, B, 0, stream>>>(h0h, h0l, h1h, h1l, h2h, h2l, jkw,
                                  WTh + 3 * 16384, WTl + 3 * 16384, fcb, outp, N);
}

// Round 7
// 381.382 us; speedup vs baseline: 1.3526x; 1.3526x over previous
//
#include <hip/hip_runtime.h>
#include <stdint.h>

typedef unsigned int  uint32;
typedef unsigned short u16;

typedef short bfx8 __attribute__((ext_vector_type(8)));
typedef float f32x4 __attribute__((ext_vector_type(4)));
typedef float f32x2 __attribute__((ext_vector_type(2)));

#define NBP 256          // padded bucket count (N <= 65536)
#define CH  2048         // edges per partition chunk

// ---------- bf16 helpers ----------
__device__ __forceinline__ float b2f(u16 u) {
    union { uint32 i; float f; } v; v.i = ((uint32)u) << 16; return v.f;
}
__device__ __forceinline__ u16 f2b(float f) {
    union { float f; uint32 i; } v; v.f = f;
    uint32 u = v.i;
    return (u16)((u + 0x7fffu + ((u >> 16) & 1u)) >> 16);   // RNE
}
__device__ __forceinline__ float blo(uint32 u) {
    union { uint32 i; float f; } v; v.i = u << 16; return v.f;
}
__device__ __forceinline__ float bhi(uint32 u) {
    union { uint32 i; float f; } v; v.i = u & 0xffff0000u; return v.f;
}
__device__ __forceinline__ uint32 packbf(float a, float b) {
    return (uint32)f2b(a) | ((uint32)f2b(b) << 16);
}
__device__ __forceinline__ void splitf(float x, u16& h, u16& l) {
    h = f2b(x);
    l = f2b(x - b2f(h));
}
__device__ __forceinline__ void split8(const float* __restrict__ p, bfx8& hi, bfx8& lo) {
    f32x4 a = *(const f32x4*)p;
    f32x4 b = *(const f32x4*)(p + 4);
    float x[8] = {a[0], a[1], a[2], a[3], b[0], b[1], b[2], b[3]};
#pragma unroll
    for (int j = 0; j < 8; ++j) {
        u16 h, l; splitf(x[j], h, l);
        hi[j] = (short)h; lo[j] = (short)l;
    }
}

// ---------- pass A: packed bucket histograms || weight split (no global atomics on N) --
__global__ __launch_bounds__(256) void k_preA(
    const int* __restrict__ row, const int* __restrict__ col, int E, int Gh,
    int* __restrict__ cntC, int* __restrict__ cntR,
    const float* __restrict__ W1, const float* __restrict__ W2,
    const float* __restrict__ W3, const float* __restrict__ fcW,
    u16* __restrict__ WTh, u16* __restrict__ WTl, int WTN) {
    if ((int)blockIdx.x < Gh) {
        __shared__ int hp[NBP];        // packed: col-count low16, row-count high16
        int t = threadIdx.x;
        hp[t] = 0;
        __syncthreads();
        int base = blockIdx.x * CH;
        int n = E - base; if (n > CH) n = CH;
        for (int i = t; i < n; i += 256) {
            int r = row[base + i], c = col[base + i];
            atomicAdd(&hp[c >> 8], 1);
            atomicAdd(&hp[r >> 8], 0x10000);
        }
        __syncthreads();
        int v = hp[t];
        if (v & 0xffff) atomicAdd(&cntC[t], v & 0xffff);
        if (v >> 16)    atomicAdd(&cntR[t], v >> 16);
        return;
    }
    int i = ((int)blockIdx.x - Gh) * 256 + threadIdx.x;
    if (i >= WTN) return;
    float w;
    if (i < 3 * 16384) {
        int m = i >> 14, j = i & 16383;     // j = fo*128 + fi
        int fo = j >> 7, fi = j & 127;
        const float* W = (m == 0) ? W1 : (m == 1) ? W2 : W3;
        w = W[fi * 128 + fo];
    } else {
        int j = i - 3 * 16384;
        int fo = j >> 7, fi = j & 127;
        w = fcW[fi * 64 + fo];
    }
    u16 h, l; splitf(w, h, l);
    WTh[i] = h; WTl[i] = l;
}

// ---------- pass B: 1 block, scans bucket counts -> offsets + cursors ----------
__global__ __launch_bounds__(256) void k_scanB(
    const int* __restrict__ cntC, const int* __restrict__ cntR,
    int* __restrict__ bOffC, int* __restrict__ bOffR,
    int* __restrict__ curC, int* __restrict__ curR, int NB) {
    int t = threadIdx.x;
    int lane = t & 63, wid = t >> 6;
    __shared__ int wsum[4];
    for (int m = 0; m < 2; ++m) {
        const int* cnt = m ? cntR : cntC;
        int* bOff = m ? bOffR : bOffC;
        int* cur  = m ? curR  : curC;
        int v = (t < NB) ? cnt[t] : 0;
        int x = v;
#pragma unroll
        for (int d = 1; d < 64; d <<= 1) {
            int u = __shfl_up(x, d);
            if (lane >= d) x += u;
        }
        if (lane == 63) wsum[wid] = x;
        __syncthreads();
        int add = 0;
        for (int i = 0; i < wid; ++i) add += wsum[i];
        int ex = x + add - v;
        if (t <= NB) bOff[t] = ex;
        cur[t] = ex;
        __syncthreads();
    }
}

// ---------- gemm body (fp32 A, split in-kernel): G = (A @ W) [* dinv], bf16 out --------
__device__ __forceinline__ void gemm128_f32_body(
    const float* __restrict__ A, const u16* __restrict__ WTh, const u16* __restrict__ WTl,
    const float* __restrict__ dinv, u16* __restrict__ G, int M, int blk) {
    const int lane = threadIdx.x & 63;
    const int q = lane >> 4, l = lane & 15;
    int rbase = blk * 128 + (threadIdx.x >> 6) * 32;
    if (rbase >= M) return;
    int r0 = rbase + l;      if (r0 >= M) r0 = M - 1;
    int r1 = rbase + 16 + l; if (r1 >= M) r1 = M - 1;

    f32x4 acc[2][8];
#pragma unroll
    for (int i = 0; i < 2; ++i)
#pragma unroll
        for (int j = 0; j < 8; ++j) acc[i][j] = (f32x4){0.f, 0.f, 0.f, 0.f};

#pragma unroll
    for (int kc = 0; kc < 4; ++kc) {
        int k0 = kc * 32 + q * 8;
        bfx8 ah0, al0, ah1, al1;
        split8(A + (size_t)r0 * 128 + k0, ah0, al0);
        split8(A + (size_t)r1 * 128 + k0, ah1, al1);
#pragma unroll
        for (int ct = 0; ct < 8; ++ct) {
            bfx8 bh = *(const bfx8*)(WTh + (ct * 16 + l) * 128 + k0);
            bfx8 bl = *(const bfx8*)(WTl + (ct * 16 + l) * 128 + k0);
            acc[0][ct] = __builtin_amdgcn_mfma_f32_16x16x32_bf16(ah0, bh, acc[0][ct], 0, 0, 0);
            acc[0][ct] = __builtin_amdgcn_mfma_f32_16x16x32_bf16(ah0, bl, acc[0][ct], 0, 0, 0);
            acc[0][ct] = __builtin_amdgcn_mfma_f32_16x16x32_bf16(al0, bh, acc[0][ct], 0, 0, 0);
            acc[1][ct] = __builtin_amdgcn_mfma_f32_16x16x32_bf16(ah1, bh, acc[1][ct], 0, 0, 0);
            acc[1][ct] = __builtin_amdgcn_mfma_f32_16x16x32_bf16(ah1, bl, acc[1][ct], 0, 0, 0);
            acc[1][ct] = __builtin_amdgcn_mfma_f32_16x16x32_bf16(al1, bh, acc[1][ct], 0, 0, 0);
        }
    }
#pragma unroll
    for (int rs = 0; rs < 2; ++rs) {
#pragma unroll
        for (int rr = 0; rr < 4; ++rr) {
            int rw = rbase + rs * 16 + q * 4 + rr;
            if (rw < M) {
                float dv = dinv ? dinv[rw] : 1.0f;
#pragma unroll
                for (int ct = 0; ct < 8; ++ct)
                    G[(size_t)rw * 128 + ct * 16 + l] = f2b(acc[rs][ct][rr] * dv);
            }
        }
    }
}

// ---------- gemm0: unscaled (dinv applied per-neighbor in agg<0>) ----------
__global__ __launch_bounds__(256) void k_gemm0(
    const float* __restrict__ A, const u16* __restrict__ WTh, const u16* __restrict__ WTl,
    u16* __restrict__ G, int M) {
    gemm128_f32_body(A, WTh, WTl, nullptr, G, M, blockIdx.x);
}

// ---------- gemm from hi/lo bf16 planes: G = (A @ W) * dinv ----------
__global__ __launch_bounds__(256) void k_gemm128_pl(
    const u16* __restrict__ Ah, const u16* __restrict__ Al,
    const u16* __restrict__ WTh, const u16* __restrict__ WTl,
    const float* __restrict__ dinv, u16* __restrict__ G, int M) {
    const int lane = threadIdx.x & 63;
    const int q = lane >> 4, l = lane & 15;
    int rbase = blockIdx.x * 128 + (threadIdx.x >> 6) * 32;
    if (rbase >= M) return;
    int r0 = rbase + l;      if (r0 >= M) r0 = M - 1;
    int r1 = rbase + 16 + l; if (r1 >= M) r1 = M - 1;

    f32x4 acc[2][8];
#pragma unroll
    for (int i = 0; i < 2; ++i)
#pragma unroll
        for (int j = 0; j < 8; ++j) acc[i][j] = (f32x4){0.f, 0.f, 0.f, 0.f};

#pragma unroll
    for (int kc = 0; kc < 4; ++kc) {
        int k0 = kc * 32 + q * 8;
        bfx8 ah0 = *(const bfx8*)(Ah + (size_t)r0 * 128 + k0);
        bfx8 al0 = *(const bfx8*)(Al + (size_t)r0 * 128 + k0);
        bfx8 ah1 = *(const bfx8*)(Ah + (size_t)r1 * 128 + k0);
        bfx8 al1 = *(const bfx8*)(Al + (size_t)r1 * 128 + k0);
#pragma unroll
        for (int ct = 0; ct < 8; ++ct) {
            bfx8 bh = *(const bfx8*)(WTh + (ct * 16 + l) * 128 + k0);
            bfx8 bl = *(const bfx8*)(WTl + (ct * 16 + l) * 128 + k0);
            acc[0][ct] = __builtin_amdgcn_mfma_f32_16x16x32_bf16(ah0, bh, acc[0][ct], 0, 0, 0);
            acc[0][ct] = __builtin_amdgcn_mfma_f32_16x16x32_bf16(ah0, bl, acc[0][ct], 0, 0, 0);
            acc[0][ct] = __builtin_amdgcn_mfma_f32_16x16x32_bf16(al0, bh, acc[0][ct], 0, 0, 0);
            acc[1][ct] = __builtin_amdgcn_mfma_f32_16x16x32_bf16(ah1, bh, acc[1][ct], 0, 0, 0);
            acc[1][ct] = __builtin_amdgcn_mfma_f32_16x16x32_bf16(ah1, bl, acc[1][ct], 0, 0, 0);
            acc[1][ct] = __builtin_amdgcn_mfma_f32_16x16x32_bf16(al1, bh, acc[1][ct], 0, 0, 0);
        }
    }
#pragma unroll
    for (int rs = 0; rs < 2; ++rs) {
#pragma unroll
        for (int rr = 0; rr < 4; ++rr) {
            int rw = rbase + rs * 16 + q * 4 + rr;
            if (rw < M) {
                float dv = dinv[rw];
#pragma unroll
                for (int ct = 0; ct < 8; ++ct)
                    G[(size_t)rw * 128 + ct * 16 + l] = f2b(acc[rs][ct][rr] * dv);
            }
        }
    }
}

// ---------- pass C: dual-direction bucket partition (partition ONLY, unfused) ---------
__global__ __launch_bounds__(256) void k_partC(
    const int* __restrict__ row, const int* __restrict__ col, int E,
    int* __restrict__ curC, int* __restrict__ curR,
    uint32* __restrict__ partC, uint32* __restrict__ partR) {
    __shared__ uint32 stagedC[CH], stagedR[CH];
    __shared__ int hp[NBP], expk[NBP], curp[NBP], runC[NBP], runR[NBP];
    __shared__ int wsum[4];
    int t = threadIdx.x;
    int lane = t & 63, wid = t >> 6;
    int base = blockIdx.x * CH;
    int n = E - base; if (n > CH) n = CH;

    int er[8], ec[8];
#pragma unroll
    for (int j = 0; j < 8; ++j) {
        int i = t + j * 256;
        if (i < n) { er[j] = row[base + i]; ec[j] = col[base + i]; }
        else er[j] = -1;
    }
    hp[t] = 0;
    __syncthreads();
#pragma unroll
    for (int j = 0; j < 8; ++j) {
        if (er[j] >= 0) {
            atomicAdd(&hp[ec[j] >> 8], 1);
            atomicAdd(&hp[er[j] >> 8], 0x10000);
        }
    }
    __syncthreads();
    int v = hp[t];
    int x = v;
#pragma unroll
    for (int d = 1; d < 64; d <<= 1) {
        int u = __shfl_up(x, d);
        if (lane >= d) x += u;
    }
    if (lane == 63) wsum[wid] = x;
    __syncthreads();
    int add = 0;
    for (int i = 0; i < wid; ++i) add += wsum[i];
    int ex = x + add - v;
    expk[t] = ex;
    curp[t] = ex;
    int vC = v & 0xffff, vR = v >> 16;
    runC[t] = vC ? atomicAdd(&curC[t], vC) : 0;
    runR[t] = vR ? atomicAdd(&curR[t], vR) : 0;
    __syncthreads();
#pragma unroll
    for (int j = 0; j < 8; ++j) {
        if (er[j] >= 0) {
            int cb = ec[j] >> 8, rb = er[j] >> 8;
            int pC = atomicAdd(&curp[cb], 1) & 0xffff;
            stagedC[pC] = ((uint32)ec[j] << 16) | (uint32)er[j];
            int pR = atomicAdd(&curp[rb], 0x10000) >> 16;
            stagedR[pR] = ((uint32)er[j] << 16) | (uint32)ec[j];
        }
    }
    __syncthreads();
    for (int i = t; i < n; i += 256) {
        uint32 pv = stagedC[i];
        int b = pv >> 24;
        partC[runC[b] + (i - (expk[b] & 0xffff))] = pv;
    }
    for (int i = t; i < n; i += 256) {
        uint32 pv = stagedR[i];
        int b = pv >> 24;
        partR[runR[b] + (i - (expk[b] >> 16))] = pv;
    }
}

// ---------- pass D: per-bucket CSR fill + dinv (from in-degree histogram) ----------
__global__ __launch_bounds__(256) void k_fillD(
    const uint32* __restrict__ partC, const uint32* __restrict__ partR,
    const int* __restrict__ bOffC, const int* __restrict__ bOffR,
    int* __restrict__ off_in, int* __restrict__ off_out,
    u16* __restrict__ csr_src, u16* __restrict__ csr_dst,
    float* __restrict__ dinv, int NB, int N, int E) {
    int part = ((int)blockIdx.x >= NB) ? 1 : 0;
    int b = (int)blockIdx.x - part * NB;
    const uint32* arr = part ? partR : partC;
    const int* bOff   = part ? bOffR : bOffC;
    int* offA         = part ? off_out : off_in;
    u16* csr          = part ? csr_dst : csr_src;
    int t = threadIdx.x;
    int lane = t & 63, wid = t >> 6;
    int base = bOff[b], end = bOff[b + 1];
    __shared__ int cnt[NBP], cur[NBP];
    __shared__ int wsum[4];
    cnt[t] = 0;
    __syncthreads();
    for (int i = base + t; i < end; i += 256)
        atomicAdd(&cnt[(arr[i] >> 16) & 255], 1);
    __syncthreads();
    int v = cnt[t];
    int x = v;
#pragma unroll
    for (int d = 1; d < 64; d <<= 1) {
        int u = __shfl_up(x, d);
        if (lane >= d) x += u;
    }
    if (lane == 63) wsum[wid] = x;
    __syncthreads();
    int add = 0;
    for (int i = 0; i < wid; ++i) add += wsum[i];
    int ex = x + add - v;
    cur[t] = ex;
    int node = (b << 8) + t;
    if (node < N) {
        offA[node] = base + ex;
        if (part == 0) dinv[node] = rsqrtf((float)(v + 1));   // in-degree + self loop
    }
    if (b == 0 && t == 0) offA[N] = E;
    __syncthreads();
    for (int i = base + t; i < end; i += 256) {
        uint32 pv = arr[i];
        int local = (pv >> 16) & 255;
        int pos = atomicAdd(&cur[local], 1);
        csr[base + pos] = (u16)(pv & 0xffffu);
    }
}

// ---------- GCN aggregate, wave-per-node, 8-unroll ----------
// MODE 0: g unscaled -> apply dinv[src] per neighbor; self uses dinv[c]; bf16 out
// MODE 1: g pre-scaled; hi/lo plane out
template <int MODE>
__global__ __launch_bounds__(256) void k_agg(
    const uint32* __restrict__ g, const u16* __restrict__ csr_src,
    const int* __restrict__ off, const float* __restrict__ dinv,
    const f32x2* __restrict__ bias, uint32* __restrict__ outH,
    uint32* __restrict__ outL, int n) {
    int w = (blockIdx.x * 256 + threadIdx.x) >> 6;
    if (w >= n) return;
    int lane = threadIdx.x & 63;
    float dc = dinv[w];
    uint32 sv = g[(size_t)w * 64 + lane];
    float s0, s1;
    if (MODE == 0) { s0 = blo(sv) * dc; s1 = bhi(sv) * dc; }
    else           { s0 = blo(sv);      s1 = bhi(sv); }
    int e = off[w], e1 = off[w + 1];
    for (; e + 8 <= e1; e += 8) {
        int ix[8];
#pragma unroll
        for (int j = 0; j < 8; ++j) ix[j] = csr_src[e + j];
        uint32 vv[8];
#pragma unroll
        for (int j = 0; j < 8; ++j) vv[j] = g[(size_t)ix[j] * 64 + lane];
        if (MODE == 0) {
            float dm[8];
#pragma unroll
            for (int j = 0; j < 8; ++j) dm[j] = dinv[ix[j]];
#pragma unroll
            for (int j = 0; j < 8; ++j) {
                s0 = fmaf(blo(vv[j]), dm[j], s0);
                s1 = fmaf(bhi(vv[j]), dm[j], s1);
            }
        } else {
#pragma unroll
            for (int j = 0; j < 8; ++j) { s0 += blo(vv[j]); s1 += bhi(vv[j]); }
        }
    }
    for (; e < e1; ++e) {
        int ix = csr_src[e];
        uint32 v = g[(size_t)ix * 64 + lane];
        if (MODE == 0) {
            float dm = dinv[ix];
            s0 = fmaf(blo(v), dm, s0);
            s1 = fmaf(bhi(v), dm, s1);
        } else {
            s0 += blo(v); s1 += bhi(v);
        }
    }
    f32x2 bb = bias[lane];
    float o0 = fmaxf(fmaf(s0, dc, bb[0]), 0.f);
    float o1 = fmaxf(fmaf(s1, dc, bb[1]), 0.f);
    if (MODE == 0) {
        outH[(size_t)w * 64 + lane] = packbf(o0, o1);
    } else {
        u16 h0, l0, h1, l1;
        splitf(o0, h0, l0);
        splitf(o1, h1, l1);
        outH[(size_t)w * 64 + lane] = (uint32)h0 | ((uint32)h1 << 16);
        outL[(size_t)w * 64 + lane] = (uint32)l0 | ((uint32)l1 << 16);
    }
}

// ---------- neighbor mean, wave-per-node -> hi/lo planes ----------
__global__ __launch_bounds__(256) void k_mean(
    const uint32* __restrict__ h, const u16* __restrict__ csr_dst,
    const int* __restrict__ off, uint32* __restrict__ outH,
    uint32* __restrict__ outL, int n) {
    int w = (blockIdx.x * 256 + threadIdx.x) >> 6;
    if (w >= n) return;
    int lane = threadIdx.x & 63;
    int e = off[w], e1 = off[w + 1];
    int d = e1 - e;
    float s0 = 0.f, s1 = 0.f;
    for (; e + 8 <= e1; e += 8) {
        int ix[8];
#pragma unroll
        for (int j = 0; j < 8; ++j) ix[j] = csr_dst[e + j];
        uint32 vv[8];
#pragma unroll
        for (int j = 0; j < 8; ++j) vv[j] = h[(size_t)ix[j] * 64 + lane];
#pragma unroll
        for (int j = 0; j < 8; ++j) { s0 += blo(vv[j]); s1 += bhi(vv[j]); }
    }
    for (; e < e1; ++e) {
        uint32 v = h[(size_t)csr_dst[e] * 64 + lane];
        s0 += blo(v); s1 += bhi(v);
    }
    float o0, o1;
    if (d > 0) {
        float inv = 1.f / (float)d;
        o0 = s0 * inv; o1 = s1 * inv;
    } else {
        uint32 sv = h[(size_t)w * 64 + lane];
        o0 = blo(sv); o1 = bhi(sv);
    }
    u16 ha, la, hb, lb;
    splitf(o0, ha, la);
    splitf(o1, hb, lb);
    outH[(size_t)w * 64 + lane] = (uint32)ha | ((uint32)hb << 16);
    outL[(size_t)w * 64 + lane] = (uint32)la | ((uint32)lb << 16);
}

// ---------- final: out = (w0*h0 + w1*h1 + w2*h2) @ fcW + fc_b ----------
__global__ __launch_bounds__(256) void k_final(
    const u16* __restrict__ h0h, const u16* __restrict__ h0l,
    const u16* __restrict__ h1h, const u16* __restrict__ h1l,
    const u16* __restrict__ h2h, const u16* __restrict__ h2l,
    const float* __restrict__ jkw,
    const u16* __restrict__ fcWTh, const u16* __restrict__ fcWTl,
    const float* __restrict__ fcb, float* __restrict__ out, int M) {
    float a0 = jkw[0], a1 = jkw[1], a2 = jkw[2];
    float mx = fmaxf(a0, fmaxf(a1, a2));
    float e0 = expf(a0 - mx), e1 = expf(a1 - mx), e2 = expf(a2 - mx);
    float inv = 1.f / (e0 + e1 + e2);
    float w0 = e0 * inv, w1 = e1 * inv, w2 = e2 * inv;

    const int lane = threadIdx.x & 63;
    const int q = lane >> 4, l = lane & 15;
    int rbase = blockIdx.x * 128 + (threadIdx.x >> 6) * 32;
    if (rbase >= M) return;
    int r0 = rbase + l;      if (r0 >= M) r0 = M - 1;
    int r1 = rbase + 16 + l; if (r1 >= M) r1 = M - 1;

    f32x4 acc[2][4];
#pragma unroll
    for (int i = 0; i < 2; ++i)
#pragma unroll
        for (int j = 0; j < 4; ++j) acc[i][j] = (f32x4){0.f, 0.f, 0.f, 0.f};

    union U8 { bfx8 v; u16 u[8]; };

#pragma unroll
    for (int kc = 0; kc < 4; ++kc) {
        int k0 = kc * 32 + q * 8;
        bfx8 ah[2], al[2];
        const int rr2[2] = {r0, r1};
#pragma unroll
        for (int half = 0; half < 2; ++half) {
            size_t o = (size_t)rr2[half] * 128 + k0;
            U8 x0h, x0l, x1h, x1l, x2h, x2l, rh, rl;
            x0h.v = *(const bfx8*)(h0h + o); x0l.v = *(const bfx8*)(h0l + o);
            x1h.v = *(const bfx8*)(h1h + o); x1l.v = *(const bfx8*)(h1l + o);
            x2h.v = *(const bfx8*)(h2h + o); x2l.v = *(const bfx8*)(h2l + o);
#pragma unroll
            for (int j = 0; j < 8; ++j) {
                float v0 = b2f(x0h.u[j]) + b2f(x0l.u[j]);
                float v1 = b2f(x1h.u[j]) + b2f(x1l.u[j]);
                float v2 = b2f(x2h.u[j]) + b2f(x2l.u[j]);
                float c = w0 * v0 + w1 * v1 + w2 * v2;
                u16 ch, cl; splitf(c, ch, cl);
                rh.u[j] = ch; rl.u[j] = cl;
            }
            ah[half] = rh.v; al[half] = rl.v;
        }
#pragma unroll
        for (int ct = 0; ct < 4; ++ct) {
            bfx8 bh = *(const bfx8*)(fcWTh + (ct * 16 + l) * 128 + k0);
            bfx8 bl = *(const bfx8*)(fcWTl + (ct * 16 + l) * 128 + k0);
#pragma unroll
            for (int half = 0; half < 2; ++half) {
                acc[half][ct] = __builtin_amdgcn_mfma_f32_16x16x32_bf16(ah[half], bh, acc[half][ct], 0, 0, 0);
                acc[half][ct] = __builtin_amdgcn_mfma_f32_16x16x32_bf16(ah[half], bl, acc[half][ct], 0, 0, 0);
                acc[half][ct] = __builtin_amdgcn_mfma_f32_16x16x32_bf16(al[half], bh, acc[half][ct], 0, 0, 0);
            }
        }
    }
#pragma unroll
    for (int rs = 0; rs < 2; ++rs) {
#pragma unroll
        for (int rr = 0; rr < 4; ++rr) {
            int rw = rbase + rs * 16 + q * 4 + rr;
            if (rw < M) {
#pragma unroll
                for (int ct = 0; ct < 4; ++ct) {
                    int cc = ct * 16 + l;
                    out[(size_t)rw * 64 + cc] = acc[rs][ct][rr] + fcb[cc];
                }
            }
        }
    }
}

extern "C" void kernel_launch(void* const* d_in, const int* in_sizes, int n_in,
                              void* d_out, int out_size, void* d_ws, size_t ws_size,
                              hipStream_t stream) {
    const int N = in_sizes[0] / 128;   // 50000
    const int E = in_sizes[1] / 2;     // 800000
    const int NB = (N + 255) >> 8;     // 196 buckets

    const float* x    = (const float*)d_in[0];
    const int* row    = (const int*)d_in[1];
    const int* col    = row + E;
    const float* W1   = (const float*)d_in[2];
    const float* b1   = (const float*)d_in[3];
    const float* W2   = (const float*)d_in[4];
    const float* b2   = (const float*)d_in[5];
    const float* W3   = (const float*)d_in[6];
    const float* b3   = (const float*)d_in[7];
    const float* jkw  = (const float*)d_in[8];
    const float* fcW  = (const float*)d_in[9];
    const float* fcb  = (const float*)d_in[10];
    float* outp       = (float*)d_out;

    char* ws = (char*)d_ws;
    size_t off = 0;
    auto alloc = [&](size_t bytes) -> char* {
        char* p = ws + off;
        off += (bytes + 255) & ~(size_t)255;
        return p;
    };
    int* cntC   = (int*)alloc((size_t)2 * NBP * sizeof(int));  // zero-init
    int* cntR   = cntC + NBP;
    int* bOffC  = (int*)alloc((size_t)(NBP + 1) * sizeof(int));
    int* bOffR  = (int*)alloc((size_t)(NBP + 1) * sizeof(int));
    int* curC   = (int*)alloc((size_t)NBP * sizeof(int));
    int* curR   = (int*)alloc((size_t)NBP * sizeof(int));
    int* off_in  = (int*)alloc((size_t)(N + 1) * sizeof(int));
    int* off_out = (int*)alloc((size_t)(N + 1) * sizeof(int));
    uint32* partC = (uint32*)alloc((size_t)E * sizeof(uint32));
    uint32* partR = (uint32*)alloc((size_t)E * sizeof(uint32));
    u16* csr_src = (u16*)alloc((size_t)E * sizeof(u16));
    u16* csr_dst = (u16*)alloc((size_t)E * sizeof(u16));
    float* dinv  = (float*)alloc((size_t)N * sizeof(float));
    const int WTN = 3 * 16384 + 8192;
    u16* WTh = (u16*)alloc((size_t)WTN * sizeof(u16));
    u16* WTl = (u16*)alloc((size_t)WTN * sizeof(u16));
    size_t FB = (size_t)N * 128 * sizeof(u16);
    u16* gbuf = (u16*)alloc(FB);
    u16* t0   = (u16*)alloc(FB);
    u16* h0h = (u16*)alloc(FB); u16* h0l = (u16*)alloc(FB);
    u16* h1h = (u16*)alloc(FB); u16* h1l = (u16*)alloc(FB);
    u16* h2h = (u16*)alloc(FB); u16* h2l = (u16*)alloc(FB);

    hipMemsetAsync(cntC, 0, (size_t)2 * NBP * sizeof(int), stream);

    const int B = 256;
    int Gh = (E + CH - 1) / CH;
    int Gwt = (WTN + B - 1) / B;
    int Gg = (N + 127) / 128;
    k_preA<<<Gh + Gwt, B, 0, stream>>>(row, col, E, Gh, cntC, cntR,
                                       W1, W2, W3, fcW, WTh, WTl, WTN);
    k_scanB<<<1, B, 0, stream>>>(cntC, cntR, bOffC, bOffR, curC, curR, NB);
    k_gemm0<<<Gg, B, 0, stream>>>(x, WTh, WTl, gbuf, N);
    k_partC<<<Gh, B, 0, stream>>>(row, col, E, curC, curR, partC, partR);
    k_fillD<<<2 * NB, B, 0, stream>>>(partC, partR, bOffC, bOffR,
                                      off_in, off_out, csr_src, csr_dst, dinv, NB, N, E);

    int aggG = (N + 3) / 4;            // 4 waves/block, 1 node/wave

    // layer 0
    k_agg<0><<<aggG, B, 0, stream>>>((const uint32*)gbuf, csr_src, off_in, dinv,
                                     (const f32x2*)b1, (uint32*)t0, nullptr, N);
    k_mean<<<aggG, B, 0, stream>>>((const uint32*)t0, csr_dst, off_out,
                                   (uint32*)h0h, (uint32*)h0l, N);
    // layer 1
    k_gemm128_pl<<<Gg, B, 0, stream>>>(h0h, h0l, WTh + 16384, WTl + 16384, dinv, gbuf, N);
    k_agg<1><<<aggG, B, 0, stream>>>((const uint32*)gbuf, csr_src, off_in, dinv,
                                     (const f32x2*)b2, (uint32*)h1h, (uint32*)h1l, N);
    // layer 2
    k_gemm128_pl<<<Gg, B, 0, stream>>>(h1h, h1l, WTh + 2 * 16384, WTl + 2 * 16384, dinv, gbuf, N);
    k_agg<1><<<aggG, B, 0, stream>>>((const uint32*)gbuf, csr_src, off_in, dinv,
                                     (const f32x2*)b3, (uint32*)h2h, (uint32*)h2l, N);
    // JK combine + final linear
    k_final<<<Gg, B, 0, stream>>>(h0h, h0l, h1h, h1l, h2h, h2l, jkw,
                                  WTh + 3 * 16384, WTl + 3 * 16384, fcb, outp, N);
}

// Round 8
// 340.094 us; speedup vs baseline: 1.5168x; 1.1214x over previous
//
#include <hip/hip_runtime.h>
#include <stdint.h>

typedef unsigned int  uint32;
typedef unsigned short u16;

typedef short bfx8 __attribute__((ext_vector_type(8)));
typedef float f32x4 __attribute__((ext_vector_type(4)));
typedef float f32x2 __attribute__((ext_vector_type(2)));

#define NBP 256          // padded bucket count (N <= 65536)
#define CH  2048         // edges per partition chunk
#define BS  4608         // fixed slots per bucket (mean 4096, sigma~64 -> 8-sigma margin)

// ---------- bf16 helpers ----------
__device__ __forceinline__ float b2f(u16 u) {
    union { uint32 i; float f; } v; v.i = ((uint32)u) << 16; return v.f;
}
__device__ __forceinline__ u16 f2b(float f) {
    union { float f; uint32 i; } v; v.f = f;
    uint32 u = v.i;
    return (u16)((u + 0x7fffu + ((u >> 16) & 1u)) >> 16);   // RNE
}
__device__ __forceinline__ float blo(uint32 u) {
    union { uint32 i; float f; } v; v.i = u << 16; return v.f;
}
__device__ __forceinline__ float bhi(uint32 u) {
    union { uint32 i; float f; } v; v.i = u & 0xffff0000u; return v.f;
}
__device__ __forceinline__ uint32 packbf(float a, float b) {
    return (uint32)f2b(a) | ((uint32)f2b(b) << 16);
}
__device__ __forceinline__ void splitf(float x, u16& h, u16& l) {
    h = f2b(x);
    l = f2b(x - b2f(h));
}
__device__ __forceinline__ void split8(const float* __restrict__ p, bfx8& hi, bfx8& lo) {
    f32x4 a = *(const f32x4*)p;
    f32x4 b = *(const f32x4*)(p + 4);
    float x[8] = {a[0], a[1], a[2], a[3], b[0], b[1], b[2], b[3]};
#pragma unroll
    for (int j = 0; j < 8; ++j) {
        u16 h, l; splitf(x[j], h, l);
        hi[j] = (short)h; lo[j] = (short)l;
    }
}

// ---------- init: block 0 sets bucket cursors; other blocks split weights ----------
__global__ __launch_bounds__(256) void k_init(
    int* __restrict__ curC, int* __restrict__ curR,
    const float* __restrict__ W1, const float* __restrict__ W2,
    const float* __restrict__ W3, const float* __restrict__ fcW,
    u16* __restrict__ WTh, u16* __restrict__ WTl, int WTN) {
    int t = threadIdx.x;
    if (blockIdx.x == 0) {
        curC[t] = t * BS;
        curR[t] = t * BS;
        return;
    }
    int i = ((int)blockIdx.x - 1) * 256 + t;
    if (i >= WTN) return;
    float w;
    if (i < 3 * 16384) {
        int m = i >> 14, j = i & 16383;     // j = fo*128 + fi
        int fo = j >> 7, fi = j & 127;
        const float* W = (m == 0) ? W1 : (m == 1) ? W2 : W3;
        w = W[fi * 128 + fo];
    } else {
        int j = i - 3 * 16384;
        int fo = j >> 7, fi = j & 127;
        w = fcW[fi * 64 + fo];
    }
    u16 h, l; splitf(w, h, l);
    WTh[i] = h; WTl[i] = l;
}

// ---------- gemm body (fp32 A, split in-kernel): G = A @ W, bf16 out (unscaled) -------
__global__ __launch_bounds__(256) void k_gemm0(
    const float* __restrict__ A, const u16* __restrict__ WTh, const u16* __restrict__ WTl,
    u16* __restrict__ G, int M) {
    const int lane = threadIdx.x & 63;
    const int q = lane >> 4, l = lane & 15;
    int rbase = blockIdx.x * 128 + (threadIdx.x >> 6) * 32;
    if (rbase >= M) return;
    int r0 = rbase + l;      if (r0 >= M) r0 = M - 1;
    int r1 = rbase + 16 + l; if (r1 >= M) r1 = M - 1;

    f32x4 acc[2][8];
#pragma unroll
    for (int i = 0; i < 2; ++i)
#pragma unroll
        for (int j = 0; j < 8; ++j) acc[i][j] = (f32x4){0.f, 0.f, 0.f, 0.f};

#pragma unroll
    for (int kc = 0; kc < 4; ++kc) {
        int k0 = kc * 32 + q * 8;
        bfx8 ah0, al0, ah1, al1;
        split8(A + (size_t)r0 * 128 + k0, ah0, al0);
        split8(A + (size_t)r1 * 128 + k0, ah1, al1);
#pragma unroll
        for (int ct = 0; ct < 8; ++ct) {
            bfx8 bh = *(const bfx8*)(WTh + (ct * 16 + l) * 128 + k0);
            bfx8 bl = *(const bfx8*)(WTl + (ct * 16 + l) * 128 + k0);
            acc[0][ct] = __builtin_amdgcn_mfma_f32_16x16x32_bf16(ah0, bh, acc[0][ct], 0, 0, 0);
            acc[0][ct] = __builtin_amdgcn_mfma_f32_16x16x32_bf16(ah0, bl, acc[0][ct], 0, 0, 0);
            acc[0][ct] = __builtin_amdgcn_mfma_f32_16x16x32_bf16(al0, bh, acc[0][ct], 0, 0, 0);
            acc[1][ct] = __builtin_amdgcn_mfma_f32_16x16x32_bf16(ah1, bh, acc[1][ct], 0, 0, 0);
            acc[1][ct] = __builtin_amdgcn_mfma_f32_16x16x32_bf16(ah1, bl, acc[1][ct], 0, 0, 0);
            acc[1][ct] = __builtin_amdgcn_mfma_f32_16x16x32_bf16(al1, bh, acc[1][ct], 0, 0, 0);
        }
    }
#pragma unroll
    for (int rs = 0; rs < 2; ++rs) {
#pragma unroll
        for (int rr = 0; rr < 4; ++rr) {
            int rw = rbase + rs * 16 + q * 4 + rr;
            if (rw < M) {
#pragma unroll
                for (int ct = 0; ct < 8; ++ct)
                    G[(size_t)rw * 128 + ct * 16 + l] = f2b(acc[rs][ct][rr]);
            }
        }
    }
}

// ---------- gemm, single bf16-plane A: G = (A @ W) * dinv, bf16 out ----------
__global__ __launch_bounds__(256) void k_gemm1p(
    const u16* __restrict__ Ah,
    const u16* __restrict__ WTh, const u16* __restrict__ WTl,
    const float* __restrict__ dinv, u16* __restrict__ G, int M) {
    const int lane = threadIdx.x & 63;
    const int q = lane >> 4, l = lane & 15;
    int rbase = blockIdx.x * 128 + (threadIdx.x >> 6) * 32;
    if (rbase >= M) return;
    int r0 = rbase + l;      if (r0 >= M) r0 = M - 1;
    int r1 = rbase + 16 + l; if (r1 >= M) r1 = M - 1;

    f32x4 acc[2][8];
#pragma unroll
    for (int i = 0; i < 2; ++i)
#pragma unroll
        for (int j = 0; j < 8; ++j) acc[i][j] = (f32x4){0.f, 0.f, 0.f, 0.f};

#pragma unroll
    for (int kc = 0; kc < 4; ++kc) {
        int k0 = kc * 32 + q * 8;
        bfx8 ah0 = *(const bfx8*)(Ah + (size_t)r0 * 128 + k0);
        bfx8 ah1 = *(const bfx8*)(Ah + (size_t)r1 * 128 + k0);
#pragma unroll
        for (int ct = 0; ct < 8; ++ct) {
            bfx8 bh = *(const bfx8*)(WTh + (ct * 16 + l) * 128 + k0);
            bfx8 bl = *(const bfx8*)(WTl + (ct * 16 + l) * 128 + k0);
            acc[0][ct] = __builtin_amdgcn_mfma_f32_16x16x32_bf16(ah0, bh, acc[0][ct], 0, 0, 0);
            acc[0][ct] = __builtin_amdgcn_mfma_f32_16x16x32_bf16(ah0, bl, acc[0][ct], 0, 0, 0);
            acc[1][ct] = __builtin_amdgcn_mfma_f32_16x16x32_bf16(ah1, bh, acc[1][ct], 0, 0, 0);
            acc[1][ct] = __builtin_amdgcn_mfma_f32_16x16x32_bf16(ah1, bl, acc[1][ct], 0, 0, 0);
        }
    }
#pragma unroll
    for (int rs = 0; rs < 2; ++rs) {
#pragma unroll
        for (int rr = 0; rr < 4; ++rr) {
            int rw = rbase + rs * 16 + q * 4 + rr;
            if (rw < M) {
                float dv = dinv[rw];
#pragma unroll
                for (int ct = 0; ct < 8; ++ct)
                    G[(size_t)rw * 128 + ct * 16 + l] = f2b(acc[rs][ct][rr] * dv);
            }
        }
    }
}

// ---------- pass C: dual-direction bucket partition into fixed-stride regions ---------
__global__ __launch_bounds__(256) void k_partC(
    const int* __restrict__ row, const int* __restrict__ col, int E,
    int* __restrict__ curC, int* __restrict__ curR,
    uint32* __restrict__ partC, uint32* __restrict__ partR) {
    __shared__ uint32 stagedC[CH], stagedR[CH];
    __shared__ int hp[NBP], expk[NBP], curp[NBP], runC[NBP], runR[NBP];
    __shared__ int wsum[4];
    int t = threadIdx.x;
    int lane = t & 63, wid = t >> 6;
    int base = blockIdx.x * CH;
    int n = E - base; if (n > CH) n = CH;

    int er[8], ec[8];
#pragma unroll
    for (int j = 0; j < 8; ++j) {
        int i = t + j * 256;
        if (i < n) { er[j] = row[base + i]; ec[j] = col[base + i]; }
        else er[j] = -1;
    }
    hp[t] = 0;
    __syncthreads();
#pragma unroll
    for (int j = 0; j < 8; ++j) {
        if (er[j] >= 0) {
            atomicAdd(&hp[ec[j] >> 8], 1);
            atomicAdd(&hp[er[j] >> 8], 0x10000);
        }
    }
    __syncthreads();
    int v = hp[t];
    int x = v;
#pragma unroll
    for (int d = 1; d < 64; d <<= 1) {
        int u = __shfl_up(x, d);
        if (lane >= d) x += u;
    }
    if (lane == 63) wsum[wid] = x;
    __syncthreads();
    int add = 0;
    for (int i = 0; i < wid; ++i) add += wsum[i];
    int ex = x + add - v;
    expk[t] = ex;
    curp[t] = ex;
    int vC = v & 0xffff, vR = v >> 16;
    runC[t] = vC ? atomicAdd(&curC[t], vC) : 0;
    runR[t] = vR ? atomicAdd(&curR[t], vR) : 0;
    __syncthreads();
#pragma unroll
    for (int j = 0; j < 8; ++j) {
        if (er[j] >= 0) {
            int cb = ec[j] >> 8, rb = er[j] >> 8;
            int pC = atomicAdd(&curp[cb], 1) & 0xffff;
            stagedC[pC] = ((uint32)ec[j] << 16) | (uint32)er[j];
            int pR = atomicAdd(&curp[rb], 0x10000) >> 16;
            stagedR[pR] = ((uint32)er[j] << 16) | (uint32)ec[j];
        }
    }
    __syncthreads();
    for (int i = t; i < n; i += 256) {
        uint32 pv = stagedC[i];
        int b = pv >> 24;
        partC[runC[b] + (i - (expk[b] & 0xffff))] = pv;
    }
    for (int i = t; i < n; i += 256) {
        uint32 pv = stagedR[i];
        int b = pv >> 24;
        partR[runR[b] + (i - (expk[b] >> 16))] = pv;
    }
}

// ---------- pass D: per-bucket CSR fill + per-node (start,end) + dinv ----------
__global__ __launch_bounds__(256) void k_fillD(
    const uint32* __restrict__ partC, const uint32* __restrict__ partR,
    const int* __restrict__ curC, const int* __restrict__ curR,
    int* __restrict__ off_in, int* __restrict__ end_in,
    int* __restrict__ off_out, int* __restrict__ end_out,
    u16* __restrict__ csr_src, u16* __restrict__ csr_dst,
    float* __restrict__ dinv, int NB, int N) {
    int part = ((int)blockIdx.x >= NB) ? 1 : 0;
    int b = (int)blockIdx.x - part * NB;
    const uint32* arr = part ? partR : partC;
    const int* curA   = part ? curR : curC;
    int* offA         = part ? off_out : off_in;
    int* endA         = part ? end_out : end_in;
    u16* csr          = part ? csr_dst : csr_src;
    int t = threadIdx.x;
    int lane = t & 63, wid = t >> 6;
    int base = b * BS, end = curA[b];
    __shared__ int cnt[NBP], cur[NBP];
    __shared__ int wsum[4];
    cnt[t] = 0;
    __syncthreads();
    for (int i = base + t; i < end; i += 256)
        atomicAdd(&cnt[(arr[i] >> 16) & 255], 1);
    __syncthreads();
    int v = cnt[t];
    int x = v;
#pragma unroll
    for (int d = 1; d < 64; d <<= 1) {
        int u = __shfl_up(x, d);
        if (lane >= d) x += u;
    }
    if (lane == 63) wsum[wid] = x;
    __syncthreads();
    int add = 0;
    for (int i = 0; i < wid; ++i) add += wsum[i];
    int ex = x + add - v;
    cur[t] = ex;
    int node = (b << 8) + t;
    if (node < N) {
        offA[node] = base + ex;
        endA[node] = base + ex + v;
        if (part == 0) dinv[node] = rsqrtf((float)(v + 1));   // in-degree + self loop
    }
    __syncthreads();
    for (int i = base + t; i < end; i += 256) {
        uint32 pv = arr[i];
        int local = (pv >> 16) & 255;
        int pos = atomicAdd(&cur[local], 1);
        csr[base + pos] = (u16)(pv & 0xffffu);
    }
}

// ---------- GCN aggregate, wave-per-node, 16-unroll ----------
// MODE 0: g unscaled -> apply dinv[src] per neighbor; self uses dinv[c]
// MODE 1: g pre-scaled
template <int MODE>
__global__ __launch_bounds__(256) void k_agg(
    const uint32* __restrict__ g, const u16* __restrict__ csr_src,
    const int* __restrict__ off, const int* __restrict__ endo,
    const float* __restrict__ dinv,
    const f32x2* __restrict__ bias, uint32* __restrict__ outH, int n) {
    int w = (blockIdx.x * 256 + threadIdx.x) >> 6;
    if (w >= n) return;
    int lane = threadIdx.x & 63;
    float dc = dinv[w];
    uint32 sv = g[(size_t)w * 64 + lane];
    float s0, s1;
    if (MODE == 0) { s0 = blo(sv) * dc; s1 = bhi(sv) * dc; }
    else           { s0 = blo(sv);      s1 = bhi(sv); }
    int e = off[w], e1 = endo[w];
    for (; e + 16 <= e1; e += 16) {
        int ix[16];
#pragma unroll
        for (int j = 0; j < 16; ++j) ix[j] = csr_src[e + j];
        uint32 vv[16];
#pragma unroll
        for (int j = 0; j < 16; ++j) vv[j] = g[(size_t)ix[j] * 64 + lane];
        if (MODE == 0) {
            float dm[16];
#pragma unroll
            for (int j = 0; j < 16; ++j) dm[j] = dinv[ix[j]];
#pragma unroll
            for (int j = 0; j < 16; ++j) {
                s0 = fmaf(blo(vv[j]), dm[j], s0);
                s1 = fmaf(bhi(vv[j]), dm[j], s1);
            }
        } else {
#pragma unroll
            for (int j = 0; j < 16; ++j) { s0 += blo(vv[j]); s1 += bhi(vv[j]); }
        }
    }
    for (; e + 4 <= e1; e += 4) {
        int ix[4];
#pragma unroll
        for (int j = 0; j < 4; ++j) ix[j] = csr_src[e + j];
        uint32 vv[4];
#pragma unroll
        for (int j = 0; j < 4; ++j) vv[j] = g[(size_t)ix[j] * 64 + lane];
        if (MODE == 0) {
            float dm[4];
#pragma unroll
            for (int j = 0; j < 4; ++j) dm[j] = dinv[ix[j]];
#pragma unroll
            for (int j = 0; j < 4; ++j) {
                s0 = fmaf(blo(vv[j]), dm[j], s0);
                s1 = fmaf(bhi(vv[j]), dm[j], s1);
            }
        } else {
#pragma unroll
            for (int j = 0; j < 4; ++j) { s0 += blo(vv[j]); s1 += bhi(vv[j]); }
        }
    }
    for (; e < e1; ++e) {
        int ix = csr_src[e];
        uint32 v = g[(size_t)ix * 64 + lane];
        if (MODE == 0) {
            float dm = dinv[ix];
            s0 = fmaf(blo(v), dm, s0);
            s1 = fmaf(bhi(v), dm, s1);
        } else {
            s0 += blo(v); s1 += bhi(v);
        }
    }
    f32x2 bb = bias[lane];
    float o0 = fmaxf(fmaf(s0, dc, bb[0]), 0.f);
    float o1 = fmaxf(fmaf(s1, dc, bb[1]), 0.f);
    outH[(size_t)w * 64 + lane] = packbf(o0, o1);
}

// ---------- neighbor mean, wave-per-node, 16-unroll, bf16 out ----------
__global__ __launch_bounds__(256) void k_mean(
    const uint32* __restrict__ h, const u16* __restrict__ csr_dst,
    const int* __restrict__ off, const int* __restrict__ endo,
    uint32* __restrict__ outH, int n) {
    int w = (blockIdx.x * 256 + threadIdx.x) >> 6;
    if (w >= n) return;
    int lane = threadIdx.x & 63;
    int e = off[w], e1 = endo[w];
    int d = e1 - e;
    float s0 = 0.f, s1 = 0.f;
    for (; e + 16 <= e1; e += 16) {
        int ix[16];
#pragma unroll
        for (int j = 0; j < 16; ++j) ix[j] = csr_dst[e + j];
        uint32 vv[16];
#pragma unroll
        for (int j = 0; j < 16; ++j) vv[j] = h[(size_t)ix[j] * 64 + lane];
#pragma unroll
        for (int j = 0; j < 16; ++j) { s0 += blo(vv[j]); s1 += bhi(vv[j]); }
    }
    for (; e + 4 <= e1; e += 4) {
        int ix[4];
#pragma unroll
        for (int j = 0; j < 4; ++j) ix[j] = csr_dst[e + j];
        uint32 vv[4];
#pragma unroll
        for (int j = 0; j < 4; ++j) vv[j] = h[(size_t)ix[j] * 64 + lane];
#pragma unroll
        for (int j = 0; j < 4; ++j) { s0 += blo(vv[j]); s1 += bhi(vv[j]); }
    }
    for (; e < e1; ++e) {
        uint32 v = h[(size_t)csr_dst[e] * 64 + lane];
        s0 += blo(v); s1 += bhi(v);
    }
    float o0, o1;
    if (d > 0) {
        float inv = 1.f / (float)d;
        o0 = s0 * inv; o1 = s1 * inv;
    } else {
        uint32 sv = h[(size_t)w * 64 + lane];
        o0 = blo(sv); o1 = bhi(sv);
    }
    outH[(size_t)w * 64 + lane] = packbf(o0, o1);
}

// ---------- final: out = (w0*h0 + w1*h1 + w2*h2) @ fcW + fc_b ----------
__global__ __launch_bounds__(256) void k_final(
    const u16* __restrict__ h0, const u16* __restrict__ h1,
    const u16* __restrict__ h2, const float* __restrict__ jkw,
    const u16* __restrict__ fcWTh, const u16* __restrict__ fcWTl,
    const float* __restrict__ fcb, float* __restrict__ out, int M) {
    float a0 = jkw[0], a1 = jkw[1], a2 = jkw[2];
    float mx = fmaxf(a0, fmaxf(a1, a2));
    float e0 = expf(a0 - mx), e1 = expf(a1 - mx), e2 = expf(a2 - mx);
    float inv = 1.f / (e0 + e1 + e2);
    float w0 = e0 * inv, w1 = e1 * inv, w2 = e2 * inv;

    const int lane = threadIdx.x & 63;
    const int q = lane >> 4, l = lane & 15;
    int rbase = blockIdx.x * 128 + (threadIdx.x >> 6) * 32;
    if (rbase >= M) return;
    int r0 = rbase + l;      if (r0 >= M) r0 = M - 1;
    int r1 = rbase + 16 + l; if (r1 >= M) r1 = M - 1;

    f32x4 acc[2][4];
#pragma unroll
    for (int i = 0; i < 2; ++i)
#pragma unroll
        for (int j = 0; j < 4; ++j) acc[i][j] = (f32x4){0.f, 0.f, 0.f, 0.f};

    union U8 { bfx8 v; u16 u[8]; };

#pragma unroll
    for (int kc = 0; kc < 4; ++kc) {
        int k0 = kc * 32 + q * 8;
        bfx8 ah[2];
        const int rr2[2] = {r0, r1};
#pragma unroll
        for (int half = 0; half < 2; ++half) {
            size_t o = (size_t)rr2[half] * 128 + k0;
            U8 x0, x1, x2, rh;
            x0.v = *(const bfx8*)(h0 + o);
            x1.v = *(const bfx8*)(h1 + o);
            x2.v = *(const bfx8*)(h2 + o);
#pragma unroll
            for (int j = 0; j < 8; ++j) {
                float c = w0 * b2f(x0.u[j]) + w1 * b2f(x1.u[j]) + w2 * b2f(x2.u[j]);
                rh.u[j] = f2b(c);
            }
            ah[half] = rh.v;
        }
#pragma unroll
        for (int ct = 0; ct < 4; ++ct) {
            bfx8 bh = *(const bfx8*)(fcWTh + (ct * 16 + l) * 128 + k0);
            bfx8 bl = *(const bfx8*)(fcWTl + (ct * 16 + l) * 128 + k0);
#pragma unroll
            for (int half = 0; half < 2; ++half) {
                acc[half][ct] = __builtin_amdgcn_mfma_f32_16x16x32_bf16(ah[half], bh, acc[half][ct], 0, 0, 0);
                acc[half][ct] = __builtin_amdgcn_mfma_f32_16x16x32_bf16(ah[half], bl, acc[half][ct], 0, 0, 0);
            }
        }
    }
#pragma unroll
    for (int rs = 0; rs < 2; ++rs) {
#pragma unroll
        for (int rr = 0; rr < 4; ++rr) {
            int rw = rbase + rs * 16 + q * 4 + rr;
            if (rw < M) {
#pragma unroll
                for (int ct = 0; ct < 4; ++ct) {
                    int cc = ct * 16 + l;
                    out[(size_t)rw * 64 + cc] = acc[rs][ct][rr] + fcb[cc];
                }
            }
        }
    }
}

extern "C" void kernel_launch(void* const* d_in, const int* in_sizes, int n_in,
                              void* d_out, int out_size, void* d_ws, size_t ws_size,
                              hipStream_t stream) {
    const int N = in_sizes[0] / 128;   // 50000
    const int E = in_sizes[1] / 2;     // 800000
    const int NB = (N + 255) >> 8;     // 196 buckets

    const float* x    = (const float*)d_in[0];
    const int* row    = (const int*)d_in[1];
    const int* col    = row + E;
    const float* W1   = (const float*)d_in[2];
    const float* b1   = (const float*)d_in[3];
    const float* W2   = (const float*)d_in[4];
    const float* b2   = (const float*)d_in[5];
    const float* W3   = (const float*)d_in[6];
    const float* b3   = (const float*)d_in[7];
    const float* jkw  = (const float*)d_in[8];
    const float* fcW  = (const float*)d_in[9];
    const float* fcb  = (const float*)d_in[10];
    float* outp       = (float*)d_out;

    char* ws = (char*)d_ws;
    size_t off = 0;
    auto alloc = [&](size_t bytes) -> char* {
        char* p = ws + off;
        off += (bytes + 255) & ~(size_t)255;
        return p;
    };
    int* curC   = (int*)alloc((size_t)NBP * sizeof(int));
    int* curR   = (int*)alloc((size_t)NBP * sizeof(int));
    int* off_in  = (int*)alloc((size_t)N * sizeof(int));
    int* end_in  = (int*)alloc((size_t)N * sizeof(int));
    int* off_out = (int*)alloc((size_t)N * sizeof(int));
    int* end_out = (int*)alloc((size_t)N * sizeof(int));
    uint32* partC = (uint32*)alloc((size_t)NBP * BS * sizeof(uint32));
    uint32* partR = (uint32*)alloc((size_t)NBP * BS * sizeof(uint32));
    u16* csr_src = (u16*)alloc((size_t)NBP * BS * sizeof(u16));
    u16* csr_dst = (u16*)alloc((size_t)NBP * BS * sizeof(u16));
    float* dinv  = (float*)alloc((size_t)N * sizeof(float));
    const int WTN = 3 * 16384 + 8192;
    u16* WTh = (u16*)alloc((size_t)WTN * sizeof(u16));
    u16* WTl = (u16*)alloc((size_t)WTN * sizeof(u16));
    size_t FB = (size_t)N * 128 * sizeof(u16);
    u16* gbuf = (u16*)alloc(FB);
    u16* t0   = (u16*)alloc(FB);
    u16* h0   = (u16*)alloc(FB);
    u16* h1   = (u16*)alloc(FB);
    u16* h2   = (u16*)alloc(FB);

    const int B = 256;
    int Gh = (E + CH - 1) / CH;
    int Gg = (N + 127) / 128;
    int Gwt = (WTN + B - 1) / B;

    k_init<<<1 + Gwt, B, 0, stream>>>(curC, curR, W1, W2, W3, fcW, WTh, WTl, WTN);
    k_gemm0<<<Gg, B, 0, stream>>>(x, WTh, WTl, gbuf, N);
    k_partC<<<Gh, B, 0, stream>>>(row, col, E, curC, curR, partC, partR);
    k_fillD<<<2 * NB, B, 0, stream>>>(partC, partR, curC, curR,
                                      off_in, end_in, off_out, end_out,
                                      csr_src, csr_dst, dinv, NB, N);

    int aggG = (N + 3) / 4;            // 4 waves/block, 1 node/wave

    // layer 0
    k_agg<0><<<aggG, B, 0, stream>>>((const uint32*)gbuf, csr_src, off_in, end_in, dinv,
                                     (const f32x2*)b1, (uint32*)t0, N);
    k_mean<<<aggG, B, 0, stream>>>((const uint32*)t0, csr_dst, off_out, end_out,
                                   (uint32*)h0, N);
    // layer 1
    k_gemm1p<<<Gg, B, 0, stream>>>(h0, WTh + 16384, WTl + 16384, dinv, gbuf, N);
    k_agg<1><<<aggG, B, 0, stream>>>((const uint32*)gbuf, csr_src, off_in, end_in, dinv,
                                     (const f32x2*)b2, (uint32*)h1, N);
    // layer 2
    k_gemm1p<<<Gg, B, 0, stream>>>(h1, WTh + 2 * 16384, WTl + 2 * 16384, dinv, gbuf, N);
    k_agg<1><<<aggG, B, 0, stream>>>((const uint32*)gbuf, csr_src, off_in, end_in, dinv,
                                     (const f32x2*)b3, (uint32*)h2, N);
    // JK combine + final linear
    k_final<<<Gg, B, 0, stream>>>(h0, h1, h2, jkw,
                                  WTh + 3 * 16384, WTl + 3 * 16384, fcb, outp, N);
}